// Round 12
// baseline (44.642 us; speedup 1.0000x reference)
//
#include <hip/hip_runtime.h>
#include <math.h>

// Problem constants (reference: POS_LEN=32, NUM_F=16, HIDDEN=256, T=32)
#define NUM_F   16
#define FIN     (8 * NUM_F)      // 128 fourier features
#define HIDDEN  256
#define TOUT    32
#define NOFF    63               // distinct offset values: -31..31
#define NSUM    125              // distinct dr+dc / dr-dc values: -62..62
#define NPAIRS_TBL (NOFF * NOFF) // 3969
#define PROWS   (NOFF + NOFF + NSUM + NSUM)      // 376 rows in P

// ---------------------------------------------------------------------------
// KP: layer-1 separable partials P[rho][h] (unchanged from R11).
//   rho 0..62 Pa(dr) | 63..125 Pb(dc) | 126..250 Pp(dr+dc) | 251..375 Pm(dr-dc)
__global__ __launch_bounds__(256) void gab_ptab_kernel(
    const float* __restrict__ freqs, const float* __restrict__ W1,
    float* __restrict__ P)
{
    __shared__ float fv[32];
    const int rho = blockIdx.x;
    int grp, val;
    if (rho < NOFF)                 { grp = 0; val = rho - 31; }
    else if (rho < 2 * NOFF)        { grp = 1; val = rho - NOFF - 31; }
    else if (rho < 2 * NOFF + NSUM) { grp = 2; val = rho - 2 * NOFF - 62; }
    else                            { grp = 3; val = rho - 2 * NOFF - NSUM - 62; }
    const int t = threadIdx.x;
    if (t < 32) {
        const float arg = (float)val * freqs[t & 15];
        fv[t] = (t < 16) ? sinf(arg) : cosf(arg);   // [sin16, cos16]
    }
    __syncthreads();
    const float4* __restrict__ w4 = (const float4*)(W1 + t * FIN + grp * 32);
    const float4* f4 = (const float4*)fv;           // same-addr broadcast
    float a0 = 0.f, a1 = 0.f, a2 = 0.f, a3 = 0.f;
    #pragma unroll
    for (int k = 0; k < 8; k += 2) {
        const float4 wa = w4[k], wb = w4[k + 1];
        const float4 fa = f4[k], fb = f4[k + 1];
        a0 = fmaf(wa.x, fa.x, a0); a1 = fmaf(wa.y, fa.y, a1);
        a2 = fmaf(wa.z, fa.z, a2); a3 = fmaf(wa.w, fa.w, a3);
        a0 = fmaf(wb.x, fb.x, a0); a1 = fmaf(wb.y, fb.y, a1);
        a2 = fmaf(wb.z, fb.z, a2); a3 = fmaf(wb.w, fb.w, a3);
    }
    P[rho * HIDDEN + t] = (a0 + a1) + (a2 + a3);
}

// ---------------------------------------------------------------------------
// Scatter-KT: one wave per pair. Compute the pair's 32 outputs (R7's proven
// zero-barrier path: lane l holds value for o = bitrev5(l&31), duplicated in
// both wave halves), then stream them to ALL output positions of that pair:
// for fixed (dr,dc) each valid i has exactly one j, and the 32 floats form
// one aligned 128-B line at out + (i*1024 + j)*32. Half-waves write 2 full
// lines per iteration. No table buffer, no gather dispatch.
__global__ __launch_bounds__(256) void gab_scatter_kernel(
    const float* __restrict__ P, const float* __restrict__ b1,
    const float* __restrict__ W2, const float* __restrict__ b2,
    float* __restrict__ out)
{
    const int pair = blockIdx.x * 4 + (threadIdx.x >> 6);
    if (pair >= NPAIRS_TBL) return;
    const int l = threadIdx.x & 63;

    // ---- row compute (proven R7 structure) ------------------------------
    const int ia = pair / NOFF;               // dr + 31
    const int ib = pair % NOFF;               // dc + 31
    const int ip = ia + ib;
    const int im = ia - ib + 62;

    const float4* __restrict__ P4 = (const float4*)P;
    const float4 pa = P4[(0 * NOFF          + ia) * 64 + l];
    const float4 pb = P4[(1 * NOFF          + ib) * 64 + l];
    const float4 pp = P4[(2 * NOFF          + ip) * 64 + l];
    const float4 pm = P4[((2 * NOFF + NSUM) + im) * 64 + l];
    const float4 bb = ((const float4*)b1)[l];
    float h0 = pa.x + pb.x + pp.x + pm.x + bb.x;
    float h1 = pa.y + pb.y + pp.y + pm.y + bb.y;
    float h2 = pa.z + pb.z + pp.z + pm.z + bb.z;
    float h3 = pa.w + pb.w + pp.w + pm.w + bb.w;
    h0 = h0 / (1.0f + expf(-h0));
    h1 = h1 / (1.0f + expf(-h1));
    h2 = h2 / (1.0f + expf(-h2));
    h3 = h3 / (1.0f + expf(-h3));

    float acc[32];
    const float4* __restrict__ W24 = (const float4*)W2;
    #pragma unroll
    for (int o = 0; o < 32; ++o) {
        const float4 w = W24[o * 64 + l];     // coalesced, W2 = 32 KB L1-hot
        acc[o] = fmaf(w.x, h0, fmaf(w.y, h1, fmaf(w.z, h2, w.w * h3)));
    }
    #pragma unroll
    for (int i = 0; i < 16; ++i) {
        const float keep = (l & 1) ? acc[i + 16] : acc[i];
        const float send = (l & 1) ? acc[i] : acc[i + 16];
        acc[i] = keep + __shfl_xor(send, 1);
    }
    #pragma unroll
    for (int i = 0; i < 8; ++i) {
        const float keep = (l & 2) ? acc[i + 8] : acc[i];
        const float send = (l & 2) ? acc[i] : acc[i + 8];
        acc[i] = keep + __shfl_xor(send, 2);
    }
    #pragma unroll
    for (int i = 0; i < 4; ++i) {
        const float keep = (l & 4) ? acc[i + 4] : acc[i];
        const float send = (l & 4) ? acc[i] : acc[i + 4];
        acc[i] = keep + __shfl_xor(send, 4);
    }
    #pragma unroll
    for (int i = 0; i < 2; ++i) {
        const float keep = (l & 8) ? acc[i + 2] : acc[i];
        const float send = (l & 8) ? acc[i] : acc[i + 2];
        acc[i] = keep + __shfl_xor(send, 8);
    }
    {
        const float keep = (l & 16) ? acc[1] : acc[0];
        const float send = (l & 16) ? acc[0] : acc[1];
        acc[0] = keep + __shfl_xor(send, 16);
    }
    const float tot = acc[0] + __shfl_xor(acc[0], 32); // both halves hold it

    const int o = ((l & 1) << 4) | ((l & 2) << 2) | (l & 4)
                | ((l & 8) >> 2) | ((l & 16) >> 4);    // bitrev5(l&31)
    const float val = (tot + b2[o]) * 0.17677669529663687f; // * 1/sqrt(32)

    // ---- scatter: enumerate the pair's (i,j) rectangle -------------------
    const int dr = ia - 31, dc = ib - 31;
    const int brmin = (dr > 0) ? dr : 0;          // i>>5 range start
    const int irmin = (dc > 0) ? dc : 0;          // i&31 range start
    const int wc = 32 - ((dc < 0) ? -dc : dc);    // width  (i&31 count)
    const int hb = 32 - ((dr < 0) ? -dr : dr);    // height (i>>5 count)
    const int count = hb * wc;                    // lines for this pair
    const unsigned M = ((1u << 20) + (unsigned)wc - 1) / (unsigned)wc; // magic

    // half-wave writes line m (lanes 0-31) and m+1 (lanes 32-63): 2 aligned
    // 128-B lines per iteration, each fully written (32 lanes x 4 B).
    for (int m = (l >> 5); m < count; m += 2) {
        const int q = (int)(((unsigned)m * M) >> 20);  // m / wc (exact, m<2^10)
        const int r = m - q * wc;                      // m % wc
        const int i = ((brmin + q) << 5) + (irmin + r);
        const int j = ((brmin + q - dr) << 5) + (irmin + r - dc);
        __builtin_nontemporal_store(val, &out[(((i << 10) + j) << 5) + o]);
    }
}

// ---------------------------------------------------------------------------
extern "C" void kernel_launch(void* const* d_in, const int* in_sizes, int n_in,
                              void* d_out, int out_size, void* d_ws, size_t ws_size,
                              hipStream_t stream) {
    // inputs: 0 seq_len 1 freqs(16) 2 W1(256*128) 3 b1(256) 4 W2(32*256)
    //         5 b2(32) 6 dr(S*S) 7 dc(S*S)
    const float* freqs = (const float*)d_in[1];
    const float* W1    = (const float*)d_in[2];
    const float* b1    = (const float*)d_in[3];
    const float* W2    = (const float*)d_in[4];
    const float* b2    = (const float*)d_in[5];
    float* out = (float*)d_out;

    float* P = (float*)d_ws;                      // 376*256*4 = 385 KB scratch

    gab_ptab_kernel   <<<PROWS, 256, 0, stream>>>(freqs, W1, P);
    gab_scatter_kernel<<<(NPAIRS_TBL + 3) / 4, 256, 0, stream>>>(P, b1, W2, b2, out);
}